// Round 10
// baseline (129.269 us; speedup 1.0000x reference)
//
#include <hip/hip_runtime.h>
#include <hip/hip_bf16.h>
#include <math.h>

// B=2, LQ=LM=2048, D=1024, H=16, DH=64. f32 I/O, bf16 MFMA internal.
// prep(cvt acts + transpose weights + prescale bias) -> Q GEMM + fused KV GEMM
// -> flash attn (swapped QK^T, 32 q/wave, lane-local P, 4-slot LDS, 1 barrier)
// -> out GEMM.

typedef __bf16 bf16;
typedef __bf16 bf16x4 __attribute__((ext_vector_type(4)));
typedef __bf16 bf16x8 __attribute__((ext_vector_type(8)));
typedef float f32x4 __attribute__((ext_vector_type(4)));

#define MFMA16(a, b, c) __builtin_amdgcn_mfma_f32_16x16x32_bf16((a), (b), (c), 0, 0, 0)

__device__ inline float exp2_hw(float x) {
    float r; asm("v_exp_f32 %0, %1" : "=v"(r) : "v"(x)); return r;   // 2^x
}

__device__ inline void gload_lds16(const bf16* g, bf16* l) {
    __builtin_amdgcn_global_load_lds(
        (const __attribute__((address_space(1))) void*)g,
        (__attribute__((address_space(3))) void*)l, 16, 0, 0);
}

// ---------------------------------------------------------------------------
// Prep: z=0 -> activations f32->bf16 (x<2048, y selects query/memory);
//       z=1,x<1024,y=0 -> weight transpose+cvt (w=x>>8, 16x16 subtiles);
//       z=1,x==1024 -> bias * log2e (y halves).
// ---------------------------------------------------------------------------
__global__ __launch_bounds__(256) void prep_kernel(
    const float* __restrict__ query, const float* __restrict__ memory,
    const float* __restrict__ mbias,
    const float* __restrict__ W0, const float* __restrict__ W1,
    const float* __restrict__ W2, const float* __restrict__ W3,
    bf16* __restrict__ Yq, bf16* __restrict__ Ym, float* __restrict__ sbias,
    bf16* __restrict__ T0, bf16* __restrict__ T1,
    bf16* __restrict__ T2, bf16* __restrict__ T3)
{
    __shared__ float Ls[64][65];
    const int t = threadIdx.x;

    if (blockIdx.z == 0) {
        const float* X = blockIdx.y ? memory : query;
        bf16* Y = blockIdx.y ? Ym : Yq;
        const size_t i = ((size_t)blockIdx.x * 256 + t) * 8;
        float4 f0 = *(const float4*)&X[i];
        float4 f1 = *(const float4*)&X[i + 4];
        bf16x8 h;
        h[0] = (bf16)f0.x; h[1] = (bf16)f0.y; h[2] = (bf16)f0.z; h[3] = (bf16)f0.w;
        h[4] = (bf16)f1.x; h[5] = (bf16)f1.y; h[6] = (bf16)f1.z; h[7] = (bf16)f1.w;
        *(bf16x8*)&Y[i] = h;
        return;
    }
    const int x = blockIdx.x;
    if (x == 1024) {                       // bias prescale (exp2 domain)
        const int i = blockIdx.y * 2048 + t * 8;
        #pragma unroll
        for (int j = 0; j < 8; ++j) sbias[i + j] = mbias[i + j] * 1.44269504f;
        return;
    }
    if (x > 1024 || blockIdx.y) return;    // idle filler blocks

    const int wsel = x >> 8, sub = x & 255;
    const float* W; bf16* T;
    switch (wsel) {
        case 0:  W = W0; T = T0; break;
        case 1:  W = W1; T = T1; break;
        case 2:  W = W2; T = T2; break;
        default: W = W3; T = T3; break;
    }
    const int n0 = (sub & 15) * 64, k0 = (sub >> 4) * 64;
    const int g = t >> 4, c = (t & 15) * 4;
    #pragma unroll
    for (int p = 0; p < 4; ++p) {
        const int row = p * 16 + g;
        float4 f = *(const float4*)&W[(size_t)(k0 + row) * 1024 + n0 + c];
        Ls[row][c + 0] = f.x; Ls[row][c + 1] = f.y;
        Ls[row][c + 2] = f.z; Ls[row][c + 3] = f.w;
    }
    __syncthreads();
    #pragma unroll
    for (int p = 0; p < 4; ++p) {
        const int n = p * 16 + g;
        bf16x4 h;
        h[0] = (bf16)Ls[c + 0][n]; h[1] = (bf16)Ls[c + 1][n];
        h[2] = (bf16)Ls[c + 2][n]; h[3] = (bf16)Ls[c + 3][n];
        *(bf16x4*)&T[(size_t)(n0 + n) * 1024 + k0 + c] = h;
    }
}

// ---------------------------------------------------------------------------
// GEMM: out = (A[M,1024](bf16) @ W + bias) * alpha, W as WT[n][k] bf16.
// BM=128, BN=64, BK=64; grid (16,32)=512. 2-phase dbuf global_load_lds.
// ---------------------------------------------------------------------------
template <typename TO>
__global__ __launch_bounds__(256) void gemm_kernel(
    const bf16* __restrict__ A, const bf16* __restrict__ WT,
    const float* __restrict__ bias, TO* __restrict__ out,
    float alpha, int mode)
{
    __shared__ __align__(16) bf16 As[2][128 * 64];
    __shared__ __align__(16) bf16 Bs[2][64 * 64];

    const int fid = blockIdx.x + (blockIdx.y << 4);
    const int swz = (fid & 7) * 64 + (fid >> 3);
    const int n0 = (swz & 15) * 64;
    const int m0 = (swz >> 4) * 128;

    const int tid = threadIdx.x;
    const int w = tid >> 6, lane = tid & 63;
    const int lr = lane & 15, lg = lane >> 4;
    const int wm = (w >> 1) * 64, wn = (w & 1) * 32;

    const int arow0 = w * 32 + (lane >> 3);
    const int brow0 = w * 16 + (lane >> 3);
    const int sch = lane & 7;

    f32x4 acc[4][2] = {};

    auto stageG = [&](int kt, int bi) {
        #pragma unroll
        for (int p = 0; p < 4; ++p) {
            const int row = arow0 + p * 8;
            const int xc = ((sch ^ (row & 7)) << 3);
            gload_lds16(&A[(size_t)(m0 + row) * 1024 + kt + xc],
                        &As[bi][row * 64 + sch * 8]);
        }
        #pragma unroll
        for (int p = 0; p < 2; ++p) {
            const int row = brow0 + p * 8;
            const int xc = ((sch ^ (row & 7)) << 3);
            gload_lds16(&WT[(size_t)(n0 + row) * 1024 + kt + xc],
                        &Bs[bi][row * 64 + sch * 8]);
        }
    };

    stageG(0, 0);
    __syncthreads();

    int cur = 0;
    #pragma unroll 1
    for (int t = 0; t < 16; ++t) {
        if (t < 15) stageG((t + 1) * 64, cur ^ 1);

        #pragma unroll
        for (int ks = 0; ks < 2; ++ks) {
            const int c = (((ks * 4 + lg) ^ (lr & 7)) << 3);
            bf16x8 af[4], bfv[2];
            #pragma unroll
            for (int mt = 0; mt < 4; ++mt)
                af[mt] = *(const bf16x8*)&As[cur][(wm + mt * 16 + lr) * 64 + c];
            #pragma unroll
            for (int nt = 0; nt < 2; ++nt)
                bfv[nt] = *(const bf16x8*)&Bs[cur][(wn + nt * 16 + lr) * 64 + c];
            #pragma unroll
            for (int nt = 0; nt < 2; ++nt)
                #pragma unroll
                for (int mt = 0; mt < 4; ++mt)
                    acc[mt][nt] = MFMA16(af[mt], bfv[nt], acc[mt][nt]);
        }
        __syncthreads();
        cur ^= 1;
    }

    #pragma unroll
    for (int nt = 0; nt < 2; ++nt) {
        const int n = n0 + wn + nt * 16 + lr;
        const float bv = bias[n];
        #pragma unroll
        for (int mt = 0; mt < 4; ++mt) {
            #pragma unroll
            for (int i = 0; i < 4; ++i) {
                const int m = m0 + wm + mt * 16 + lg * 4 + i;
                const float v = (acc[mt][nt][i] + bv) * alpha;
                if (mode == 0) {
                    out[(size_t)m * 1024 + n] = (TO)v;
                } else {
                    const int b = m >> 11, t2 = m & 2047;
                    out[((size_t)(b << 10) + n) * 2048 + t2] = (TO)v;
                }
            }
        }
    }
}

// ---------------------------------------------------------------------------
// Fused K+V GEMM: stages A (memory) once, both WTk/WTv B-tiles.
// ---------------------------------------------------------------------------
__global__ __launch_bounds__(256) void gemm_kv_kernel(
    const bf16* __restrict__ A, const bf16* __restrict__ WTk,
    const bf16* __restrict__ WTv, const float* __restrict__ bk,
    const float* __restrict__ bv, bf16* __restrict__ Kout,
    bf16* __restrict__ Vtout)
{
    __shared__ __align__(16) bf16 As[2][128 * 64];
    __shared__ __align__(16) bf16 Bk[2][64 * 64];
    __shared__ __align__(16) bf16 Bv[2][64 * 64];

    const int fid = blockIdx.x + (blockIdx.y << 4);
    const int swz = (fid & 7) * 64 + (fid >> 3);
    const int n0 = (swz & 15) * 64;
    const int m0 = (swz >> 4) * 128;

    const int tid = threadIdx.x;
    const int w = tid >> 6, lane = tid & 63;
    const int lr = lane & 15, lg = lane >> 4;
    const int wm = (w >> 1) * 64, wn = (w & 1) * 32;

    const int arow0 = w * 32 + (lane >> 3);
    const int brow0 = w * 16 + (lane >> 3);
    const int sch = lane & 7;

    f32x4 accK[4][2] = {}, accV[4][2] = {};

    auto stageG = [&](int kt, int bi) {
        #pragma unroll
        for (int p = 0; p < 4; ++p) {
            const int row = arow0 + p * 8;
            const int xc = ((sch ^ (row & 7)) << 3);
            gload_lds16(&A[(size_t)(m0 + row) * 1024 + kt + xc],
                        &As[bi][row * 64 + sch * 8]);
        }
        #pragma unroll
        for (int p = 0; p < 2; ++p) {
            const int row = brow0 + p * 8;
            const int xc = ((sch ^ (row & 7)) << 3);
            gload_lds16(&WTk[(size_t)(n0 + row) * 1024 + kt + xc],
                        &Bk[bi][row * 64 + sch * 8]);
            gload_lds16(&WTv[(size_t)(n0 + row) * 1024 + kt + xc],
                        &Bv[bi][row * 64 + sch * 8]);
        }
    };

    stageG(0, 0);
    __syncthreads();

    int cur = 0;
    #pragma unroll 1
    for (int t = 0; t < 16; ++t) {
        if (t < 15) stageG((t + 1) * 64, cur ^ 1);

        #pragma unroll
        for (int ks = 0; ks < 2; ++ks) {
            const int c = (((ks * 4 + lg) ^ (lr & 7)) << 3);
            bf16x8 af[4], bkf[2], bvf[2];
            #pragma unroll
            for (int mt = 0; mt < 4; ++mt)
                af[mt] = *(const bf16x8*)&As[cur][(wm + mt * 16 + lr) * 64 + c];
            #pragma unroll
            for (int nt = 0; nt < 2; ++nt) {
                bkf[nt] = *(const bf16x8*)&Bk[cur][(wn + nt * 16 + lr) * 64 + c];
                bvf[nt] = *(const bf16x8*)&Bv[cur][(wn + nt * 16 + lr) * 64 + c];
            }
            #pragma unroll
            for (int nt = 0; nt < 2; ++nt)
                #pragma unroll
                for (int mt = 0; mt < 4; ++mt) {
                    accK[mt][nt] = MFMA16(af[mt], bkf[nt], accK[mt][nt]);
                    accV[mt][nt] = MFMA16(af[mt], bvf[nt], accV[mt][nt]);
                }
        }
        __syncthreads();
        cur ^= 1;
    }

    #pragma unroll
    for (int nt = 0; nt < 2; ++nt) {
        const int n = n0 + wn + nt * 16 + lr;
        const float bkv = bk[n], bvv = bv[n];
        #pragma unroll
        for (int mt = 0; mt < 4; ++mt) {
            #pragma unroll
            for (int i = 0; i < 4; ++i) {
                const int m = m0 + wm + mt * 16 + lg * 4 + i;
                Kout[(size_t)m * 1024 + n] = (bf16)(accK[mt][nt][i] + bkv);
                const int b = m >> 11, t2 = m & 2047;
                Vtout[((size_t)(b << 10) + n) * 2048 + t2] = (bf16)(accV[mt][nt][i] + bvv);
            }
        }
    }
}

// ---------------------------------------------------------------------------
// Flash attention v7: swapped QK^T, 32 q-rows/wave (2 Q-frags sharing all K/V
// LDS reads -> halves LDS-reads-per-FLOP). Grid (16,16,2)=512 blocks, 256 thr
// (4 waves), 2 blocks/CU. 4-slot LDS, ONE barrier/iter, counted vmcnt(8).
// Lane-local P (no LDS round-trip). Pre-scaled bias (exp2 domain).
// ---------------------------------------------------------------------------
__global__ __launch_bounds__(256) void attn_kernel(
    const bf16* __restrict__ Q, const bf16* __restrict__ K,
    const bf16* __restrict__ Vt, const float* __restrict__ sbias,
    bf16* __restrict__ Oout)
{
    __shared__ __align__(16) bf16 Kbuf[4][4096];   // 64 keys x 64 d (pi rows)
    __shared__ __align__(16) bf16 Vbuf[4][4096];   // 64 d x 64 keys

    const int tid = threadIdx.x;
    const int w = tid >> 6, lane = tid & 63;
    const int lr = lane & 15, lg = lane >> 4;

    const int fid = blockIdx.x + (blockIdx.y << 4) + (blockIdx.z << 8);
    const int swz = (fid & 7) * 64 + (fid >> 3);
    const int qt = swz & 15, head = (swz >> 4) & 15, b = swz >> 8;
    const int qrow = qt * 128 + w * 32;

    // Q as B-operand, 2 fragments (q rows qrow+g*16+lr)
    bf16x8 qf[2][2];
    #pragma unroll
    for (int g = 0; g < 2; ++g) {
        const size_t qo = (size_t)(b * 2048 + qrow + g * 16 + lr) * 1024 + head * 64;
        qf[g][0] = *(const bf16x8*)&Q[qo + lg * 8];
        qf[g][1] = *(const bf16x8*)&Q[qo + 32 + lg * 8];
    }

    const bf16* Kb = K + (size_t)b * 2048 * 1024 + head * 64;
    const bf16* Vb = Vt + ((size_t)b * 1024 + head * 64) * 2048;
    const float* biasb = sbias + b * 2048;

    float m_run[2] = {-INFINITY, -INFINITY};
    f32x4 of[2][4] = {};
    f32x4 ofl[2] = {};

    bf16x8 ones8;
    #pragma unroll
    for (int j = 0; j < 8; ++j) ones8[j] = (bf16)1.0f;

    // staging: 512 K-chunks + 512 V-chunks per tile over 256 thr = 2+2 gloads.
    // K rows pi-permuted so the PV B-fragment is lane-local.
    auto stage = [&](int t, int slot) {
        #pragma unroll
        for (int cp = 0; cp < 2; ++cp) {
            const int chunk = cp * 256 + tid;
            const int R = chunk >> 3, cc = chunk & 7;
            const int cs = cc ^ (R & 7);
            const int piR = ((R & 16) << 1) | ((R & 12) << 1) | ((R & 32) >> 3) | (R & 3);
            gload_lds16(Kb + (size_t)(t * 64 + piR) * 1024 + cs * 8,
                        &Kbuf[slot][chunk * 8]);
            gload_lds16(Vb + (size_t)R * 2048 + t * 64 + cs * 8,
                        &Vbuf[slot][chunk * 8]);
        }
    };

    stage(0, 0);
    stage(1, 1);

    #pragma unroll 1
    for (int it = 0; it < 32; ++it) {
        const int slot = it & 3;
        const int tn = (it < 30) ? it + 2 : 31;
        stage(tn, (it + 2) & 3);
        asm volatile("s_waitcnt vmcnt(8)" ::: "memory");   // tile `it` landed
        __builtin_amdgcn_s_barrier();
        __builtin_amdgcn_sched_barrier(0);

        // bias for this tile (pre-scaled), shared by both q-frags
        const int bt = it * 64;
        f32x4 b4[4];
        b4[0] = *(const f32x4*)&biasb[bt + 8 * lg];
        b4[1] = *(const f32x4*)&biasb[bt + 32 + 8 * lg];
        b4[2] = *(const f32x4*)&biasb[bt + 4 + 8 * lg];
        b4[3] = *(const f32x4*)&biasb[bt + 36 + 8 * lg];

        // ---- S^T = bias + K Q^T (both frags share kf) ----
        f32x4 s[2][4];
        #pragma unroll
        for (int g = 0; g < 2; ++g)
            #pragma unroll
            for (int nt = 0; nt < 4; ++nt) s[g][nt] = b4[nt];
        #pragma unroll
        for (int ks = 0; ks < 2; ++ks) {
            const int cw = (((ks * 4 + lg) ^ (lr & 7)) << 3);
            bf16x8 kf[4];
            #pragma unroll
            for (int nt = 0; nt < 4; ++nt)
                kf[nt] = *(const bf16x8*)&Kbuf[slot][(nt * 16 + lr) * 64 + cw];
            __builtin_amdgcn_s_setprio(1);
            #pragma unroll
            for (int nt = 0; nt < 4; ++nt) {
                s[0][nt] = MFMA16(kf[nt], qf[0][ks], s[0][nt]);
                s[1][nt] = MFMA16(kf[nt], qf[1][ks], s[1][nt]);
            }
            __builtin_amdgcn_s_setprio(0);
        }

        // ---- in-lane max; defer-max ----
        float rml[2];
        #pragma unroll
        for (int g = 0; g < 2; ++g) {
            float m0 = fmaxf(fmaxf(s[g][0][0], s[g][0][1]), fmaxf(s[g][0][2], s[g][0][3]));
            float m1 = fmaxf(fmaxf(s[g][1][0], s[g][1][1]), fmaxf(s[g][1][2], s[g][1][3]));
            float m2 = fmaxf(fmaxf(s[g][2][0], s[g][2][1]), fmaxf(s[g][2][2], s[g][2][3]));
            float m3 = fmaxf(fmaxf(s[g][3][0], s[g][3][1]), fmaxf(s[g][3][2], s[g][3][3]));
            rml[g] = fmaxf(fmaxf(m0, m1), fmaxf(m2, m3));
        }
        const bool need = (rml[0] > m_run[0] + 8.f) || (rml[1] > m_run[1] + 8.f);

        if (__any(need)) {            // rare: reduce + rescale both frags
            #pragma unroll
            for (int g = 0; g < 2; ++g) {
                float mx = fmaxf(rml[g], __shfl_xor(rml[g], 16, 64));
                mx = fmaxf(mx, __shfl_xor(mx, 32, 64));
                const float mnew = fmaxf(m_run[g], mx);
                const float al = exp2_hw(m_run[g] - mnew);
                m_run[g] = mnew;
                ofl[g] *= al;
                #pragma unroll
                for (int dt = 0; dt < 4; ++dt) of[g][dt] *= al;
            }
        }

        // ---- P = exp2(S - m) into lane-local B-fragments ----
        bf16x8 pb[2][2];
        #pragma unroll
        for (int g = 0; g < 2; ++g)
            #pragma unroll
            for (int i = 0; i < 4; ++i) {
                pb[g][0][i]     = (bf16)exp2_hw(s[g][0][i] - m_run[g]);
                pb[g][1][i]     = (bf16)exp2_hw(s[g][1][i] - m_run[g]);
                pb[g][0][4 + i] = (bf16)exp2_hw(s[g][2][i] - m_run[g]);
                pb[g][1][4 + i] = (bf16)exp2_hw(s[g][3][i] - m_run[g]);
            }

        // ---- O^T += V^T P^T ; l += 1·P^T (vf shared by both frags) ----
        __builtin_amdgcn_s_setprio(1);
        #pragma unroll
        for (int ks = 0; ks < 2; ++ks) {
            const int cw = (((ks * 4 + lg) ^ (lr & 7)) << 3);
            bf16x8 vf[4];
            #pragma unroll
            for (int dt = 0; dt < 4; ++dt)
                vf[dt] = *(const bf16x8*)&Vbuf[slot][(dt * 16 + lr) * 64 + cw];
            #pragma unroll
            for (int g = 0; g < 2; ++g) {
                #pragma unroll
                for (int dt = 0; dt < 4; ++dt)
                    of[g][dt] = MFMA16(vf[dt], pb[g][ks], of[g][dt]);
                ofl[g] = MFMA16(ones8, pb[g][ks], ofl[g]);
            }
        }
        __builtin_amdgcn_s_setprio(0);
    }

    // ---- finalize ----
    #pragma unroll
    for (int g = 0; g < 2; ++g) {
        const float inv = 1.0f / ofl[g][0];
        const size_t ob = (size_t)(b * 2048 + qrow + g * 16 + lr) * 1024 + head * 64;
        #pragma unroll
        for (int dt = 0; dt < 4; ++dt) {
            bf16x4 h4;
            #pragma unroll
            for (int i = 0; i < 4; ++i) h4[i] = (bf16)(of[g][dt][i] * inv);
            *(bf16x4*)&Oout[ob + dt * 16 + lg * 4] = h4;
        }
    }
}

// ---------------------------------------------------------------------------
extern "C" void kernel_launch(void* const* d_in, const int* in_sizes, int n_in,
                              void* d_out, int out_size, void* d_ws, size_t ws_size,
                              hipStream_t stream) {
    const float* query  = (const float*)d_in[0];
    const float* memory = (const float*)d_in[1];
    const float* mbias  = (const float*)d_in[2];
    const float* Wq = (const float*)d_in[3];
    const float* bq = (const float*)d_in[4];
    const float* Wk = (const float*)d_in[5];
    const float* bk = (const float*)d_in[6];
    const float* Wv = (const float*)d_in[7];
    const float* bv = (const float*)d_in[8];
    const float* Wo = (const float*)d_in[9];
    const float* bo = (const float*)d_in[10];
    float* out = (float*)d_out;

    const size_t SZ = 4096ull * 1024ull * sizeof(bf16);   // 8 MiB
    const size_t WZ = 1024ull * 1024ull * sizeof(bf16);   // 2 MiB
    char* ws = (char*)d_ws;
    bf16* Qp  = (bf16*)(ws);
    bf16* Kp  = (bf16*)(ws + SZ);       // also query_bf16 staging
    bf16* Vtp = (bf16*)(ws + 2 * SZ);
    bf16* Ap  = (bf16*)(ws + 3 * SZ);   // also memory_bf16 staging
    bf16* WTq = (bf16*)(ws + 4 * SZ);
    bf16* WTk = (bf16*)(ws + 4 * SZ + WZ);
    bf16* WTv = (bf16*)(ws + 4 * SZ + 2 * WZ);
    bf16* WTo = (bf16*)(ws + 4 * SZ + 3 * WZ);
    float* sbias = (float*)(ws + 4 * SZ + 4 * WZ);        // 16 KiB

    dim3 blk(256);
    prep_kernel<<<dim3(2048, 2, 2), blk, 0, stream>>>(
        query, memory, mbias, Wq, Wk, Wv, Wo, Kp, Ap, sbias, WTq, WTk, WTv, WTo);

    dim3 gg(16, 32);
    // Q scaled by DH^-0.5 * log2(e): softmax runs in exp2 domain.
    gemm_kernel<bf16><<<gg, blk, 0, stream>>>(Kp, WTq, bq, Qp, 0.18033688f, 0);
    gemm_kv_kernel<<<gg, blk, 0, stream>>>(Ap, WTk, WTv, bk, bv, Kp, Vtp);
    attn_kernel<<<dim3(16, 16, 2), blk, 0, stream>>>(Qp, Kp, Vtp, sbias, Ap);
    gemm_kernel<float><<<gg, blk, 0, stream>>>(Ap, WTo, bo, out, 1.0f, 0);
}

// Round 11
// 120.737 us; speedup vs baseline: 1.0707x; 1.0707x over previous
//
#include <hip/hip_runtime.h>
#include <hip/hip_bf16.h>
#include <math.h>

// B=2, LQ=LM=2048, D=1024, H=16, DH=64. f32 I/O, bf16 MFMA internal.
// prep -> Q GEMM + fused KV GEMM -> flash attn (swapped QK^T, 32 q/wave,
// 8-wave blocks, 1 block/CU, lane-local P, 4-slot LDS, 1 barrier) -> out GEMM.

typedef __bf16 bf16;
typedef __bf16 bf16x4 __attribute__((ext_vector_type(4)));
typedef __bf16 bf16x8 __attribute__((ext_vector_type(8)));
typedef float f32x4 __attribute__((ext_vector_type(4)));

#define MFMA16(a, b, c) __builtin_amdgcn_mfma_f32_16x16x32_bf16((a), (b), (c), 0, 0, 0)

__device__ inline float exp2_hw(float x) {
    float r; asm("v_exp_f32 %0, %1" : "=v"(r) : "v"(x)); return r;   // 2^x
}

__device__ inline void gload_lds16(const bf16* g, bf16* l) {
    __builtin_amdgcn_global_load_lds(
        (const __attribute__((address_space(1))) void*)g,
        (__attribute__((address_space(3))) void*)l, 16, 0, 0);
}

// ---------------------------------------------------------------------------
// Prep: z=0 -> activations f32->bf16; z=1,x<1024 -> weight transpose+cvt;
//       z=1,x==1024 -> bias * log2e.
// ---------------------------------------------------------------------------
__global__ __launch_bounds__(256) void prep_kernel(
    const float* __restrict__ query, const float* __restrict__ memory,
    const float* __restrict__ mbias,
    const float* __restrict__ W0, const float* __restrict__ W1,
    const float* __restrict__ W2, const float* __restrict__ W3,
    bf16* __restrict__ Yq, bf16* __restrict__ Ym, float* __restrict__ sbias,
    bf16* __restrict__ T0, bf16* __restrict__ T1,
    bf16* __restrict__ T2, bf16* __restrict__ T3)
{
    __shared__ float Ls[64][65];
    const int t = threadIdx.x;

    if (blockIdx.z == 0) {
        const float* X = blockIdx.y ? memory : query;
        bf16* Y = blockIdx.y ? Ym : Yq;
        const size_t i = ((size_t)blockIdx.x * 256 + t) * 8;
        float4 f0 = *(const float4*)&X[i];
        float4 f1 = *(const float4*)&X[i + 4];
        bf16x8 h;
        h[0] = (bf16)f0.x; h[1] = (bf16)f0.y; h[2] = (bf16)f0.z; h[3] = (bf16)f0.w;
        h[4] = (bf16)f1.x; h[5] = (bf16)f1.y; h[6] = (bf16)f1.z; h[7] = (bf16)f1.w;
        *(bf16x8*)&Y[i] = h;
        return;
    }
    const int x = blockIdx.x;
    if (x == 1024) {
        const int i = blockIdx.y * 2048 + t * 8;
        #pragma unroll
        for (int j = 0; j < 8; ++j) sbias[i + j] = mbias[i + j] * 1.44269504f;
        return;
    }
    if (x > 1024 || blockIdx.y) return;

    const int wsel = x >> 8, sub = x & 255;
    const float* W; bf16* T;
    switch (wsel) {
        case 0:  W = W0; T = T0; break;
        case 1:  W = W1; T = T1; break;
        case 2:  W = W2; T = T2; break;
        default: W = W3; T = T3; break;
    }
    const int n0 = (sub & 15) * 64, k0 = (sub >> 4) * 64;
    const int g = t >> 4, c = (t & 15) * 4;
    #pragma unroll
    for (int p = 0; p < 4; ++p) {
        const int row = p * 16 + g;
        float4 f = *(const float4*)&W[(size_t)(k0 + row) * 1024 + n0 + c];
        Ls[row][c + 0] = f.x; Ls[row][c + 1] = f.y;
        Ls[row][c + 2] = f.z; Ls[row][c + 3] = f.w;
    }
    __syncthreads();
    #pragma unroll
    for (int p = 0; p < 4; ++p) {
        const int n = p * 16 + g;
        bf16x4 h;
        h[0] = (bf16)Ls[c + 0][n]; h[1] = (bf16)Ls[c + 1][n];
        h[2] = (bf16)Ls[c + 2][n]; h[3] = (bf16)Ls[c + 3][n];
        *(bf16x4*)&T[(size_t)(n0 + n) * 1024 + k0 + c] = h;
    }
}

// ---------------------------------------------------------------------------
// GEMM: out = (A[M,1024](bf16) @ W + bias) * alpha, W as WT[n][k] bf16.
// BM=128, BN=64, BK=64; grid (16,32)=512. 2-phase dbuf global_load_lds.
// ---------------------------------------------------------------------------
template <typename TO>
__global__ __launch_bounds__(256) void gemm_kernel(
    const bf16* __restrict__ A, const bf16* __restrict__ WT,
    const float* __restrict__ bias, TO* __restrict__ out,
    float alpha, int mode)
{
    __shared__ __align__(16) bf16 As[2][128 * 64];
    __shared__ __align__(16) bf16 Bs[2][64 * 64];

    const int fid = blockIdx.x + (blockIdx.y << 4);
    const int swz = (fid & 7) * 64 + (fid >> 3);
    const int n0 = (swz & 15) * 64;
    const int m0 = (swz >> 4) * 128;

    const int tid = threadIdx.x;
    const int w = tid >> 6, lane = tid & 63;
    const int lr = lane & 15, lg = lane >> 4;
    const int wm = (w >> 1) * 64, wn = (w & 1) * 32;

    const int arow0 = w * 32 + (lane >> 3);
    const int brow0 = w * 16 + (lane >> 3);
    const int sch = lane & 7;

    f32x4 acc[4][2] = {};

    auto stageG = [&](int kt, int bi) {
        #pragma unroll
        for (int p = 0; p < 4; ++p) {
            const int row = arow0 + p * 8;
            const int xc = ((sch ^ (row & 7)) << 3);
            gload_lds16(&A[(size_t)(m0 + row) * 1024 + kt + xc],
                        &As[bi][row * 64 + sch * 8]);
        }
        #pragma unroll
        for (int p = 0; p < 2; ++p) {
            const int row = brow0 + p * 8;
            const int xc = ((sch ^ (row & 7)) << 3);
            gload_lds16(&WT[(size_t)(n0 + row) * 1024 + kt + xc],
                        &Bs[bi][row * 64 + sch * 8]);
        }
    };

    stageG(0, 0);
    __syncthreads();

    int cur = 0;
    #pragma unroll 1
    for (int t = 0; t < 16; ++t) {
        if (t < 15) stageG((t + 1) * 64, cur ^ 1);

        #pragma unroll
        for (int ks = 0; ks < 2; ++ks) {
            const int c = (((ks * 4 + lg) ^ (lr & 7)) << 3);
            bf16x8 af[4], bfv[2];
            #pragma unroll
            for (int mt = 0; mt < 4; ++mt)
                af[mt] = *(const bf16x8*)&As[cur][(wm + mt * 16 + lr) * 64 + c];
            #pragma unroll
            for (int nt = 0; nt < 2; ++nt)
                bfv[nt] = *(const bf16x8*)&Bs[cur][(wn + nt * 16 + lr) * 64 + c];
            #pragma unroll
            for (int nt = 0; nt < 2; ++nt)
                #pragma unroll
                for (int mt = 0; mt < 4; ++mt)
                    acc[mt][nt] = MFMA16(af[mt], bfv[nt], acc[mt][nt]);
        }
        __syncthreads();
        cur ^= 1;
    }

    #pragma unroll
    for (int nt = 0; nt < 2; ++nt) {
        const int n = n0 + wn + nt * 16 + lr;
        const float bv = bias[n];
        #pragma unroll
        for (int mt = 0; mt < 4; ++mt) {
            #pragma unroll
            for (int i = 0; i < 4; ++i) {
                const int m = m0 + wm + mt * 16 + lg * 4 + i;
                const float v = (acc[mt][nt][i] + bv) * alpha;
                if (mode == 0) {
                    out[(size_t)m * 1024 + n] = (TO)v;
                } else {
                    const int b = m >> 11, t2 = m & 2047;
                    out[((size_t)(b << 10) + n) * 2048 + t2] = (TO)v;
                }
            }
        }
    }
}

// ---------------------------------------------------------------------------
// Fused K+V GEMM: stages A (memory) once, both WTk/WTv B-tiles.
// ---------------------------------------------------------------------------
__global__ __launch_bounds__(256) void gemm_kv_kernel(
    const bf16* __restrict__ A, const bf16* __restrict__ WTk,
    const bf16* __restrict__ WTv, const float* __restrict__ bk,
    const float* __restrict__ bv, bf16* __restrict__ Kout,
    bf16* __restrict__ Vtout)
{
    __shared__ __align__(16) bf16 As[2][128 * 64];
    __shared__ __align__(16) bf16 Bk[2][64 * 64];
    __shared__ __align__(16) bf16 Bv[2][64 * 64];

    const int fid = blockIdx.x + (blockIdx.y << 4);
    const int swz = (fid & 7) * 64 + (fid >> 3);
    const int n0 = (swz & 15) * 64;
    const int m0 = (swz >> 4) * 128;

    const int tid = threadIdx.x;
    const int w = tid >> 6, lane = tid & 63;
    const int lr = lane & 15, lg = lane >> 4;
    const int wm = (w >> 1) * 64, wn = (w & 1) * 32;

    const int arow0 = w * 32 + (lane >> 3);
    const int brow0 = w * 16 + (lane >> 3);
    const int sch = lane & 7;

    f32x4 accK[4][2] = {}, accV[4][2] = {};

    auto stageG = [&](int kt, int bi) {
        #pragma unroll
        for (int p = 0; p < 4; ++p) {
            const int row = arow0 + p * 8;
            const int xc = ((sch ^ (row & 7)) << 3);
            gload_lds16(&A[(size_t)(m0 + row) * 1024 + kt + xc],
                        &As[bi][row * 64 + sch * 8]);
        }
        #pragma unroll
        for (int p = 0; p < 2; ++p) {
            const int row = brow0 + p * 8;
            const int xc = ((sch ^ (row & 7)) << 3);
            gload_lds16(&WTk[(size_t)(n0 + row) * 1024 + kt + xc],
                        &Bk[bi][row * 64 + sch * 8]);
            gload_lds16(&WTv[(size_t)(n0 + row) * 1024 + kt + xc],
                        &Bv[bi][row * 64 + sch * 8]);
        }
    };

    stageG(0, 0);
    __syncthreads();

    int cur = 0;
    #pragma unroll 1
    for (int t = 0; t < 16; ++t) {
        if (t < 15) stageG((t + 1) * 64, cur ^ 1);

        #pragma unroll
        for (int ks = 0; ks < 2; ++ks) {
            const int c = (((ks * 4 + lg) ^ (lr & 7)) << 3);
            bf16x8 af[4], bkf[2], bvf[2];
            #pragma unroll
            for (int mt = 0; mt < 4; ++mt)
                af[mt] = *(const bf16x8*)&As[cur][(wm + mt * 16 + lr) * 64 + c];
            #pragma unroll
            for (int nt = 0; nt < 2; ++nt) {
                bkf[nt] = *(const bf16x8*)&Bk[cur][(wn + nt * 16 + lr) * 64 + c];
                bvf[nt] = *(const bf16x8*)&Bv[cur][(wn + nt * 16 + lr) * 64 + c];
            }
            #pragma unroll
            for (int nt = 0; nt < 2; ++nt)
                #pragma unroll
                for (int mt = 0; mt < 4; ++mt) {
                    accK[mt][nt] = MFMA16(af[mt], bkf[nt], accK[mt][nt]);
                    accV[mt][nt] = MFMA16(af[mt], bvf[nt], accV[mt][nt]);
                }
        }
        __syncthreads();
        cur ^= 1;
    }

    #pragma unroll
    for (int nt = 0; nt < 2; ++nt) {
        const int n = n0 + wn + nt * 16 + lr;
        const float bkv = bk[n], bvv = bv[n];
        #pragma unroll
        for (int mt = 0; mt < 4; ++mt) {
            #pragma unroll
            for (int i = 0; i < 4; ++i) {
                const int m = m0 + wm + mt * 16 + lg * 4 + i;
                Kout[(size_t)m * 1024 + n] = (bf16)(accK[mt][nt][i] + bkv);
                const int b = m >> 11, t2 = m & 2047;
                Vtout[((size_t)(b << 10) + n) * 2048 + t2] = (bf16)(accV[mt][nt][i] + bvv);
            }
        }
    }
}

// ---------------------------------------------------------------------------
// Flash attention v8: swapped QK^T, 32 q/wave, 8-wave blocks (512 thr),
// grid (8,16,2)=256 blocks = 1 block/CU. K/V 4-slot LDS, one barrier/iter,
// counted vmcnt(4) (2 staging loads/thread). Bias double-buffered (prefetched
// a tile ahead -> no chain-head latency). V fragments loaded early (overlap
// softmax). Lane-local P via pi-permuted K rows.
// ---------------------------------------------------------------------------
__global__ __launch_bounds__(512) void attn_kernel(
    const bf16* __restrict__ Q, const bf16* __restrict__ K,
    const bf16* __restrict__ Vt, const float* __restrict__ sbias,
    bf16* __restrict__ Oout)
{
    __shared__ __align__(16) bf16 Kbuf[4][4096];   // 64 keys x 64 d (pi rows)
    __shared__ __align__(16) bf16 Vbuf[4][4096];   // 64 d x 64 keys

    const int tid = threadIdx.x;
    const int w = tid >> 6, lane = tid & 63;
    const int lr = lane & 15, lg = lane >> 4;

    // 256 blocks: XCD chunk of 32 = 4 (head,b) groups x 8 q-tiles
    const int fid = blockIdx.x + (blockIdx.y << 3) + (blockIdx.z << 7);
    const int swz = (fid & 7) * 32 + (fid >> 3);
    const int qt = swz & 7, head = (swz >> 3) & 15, b = swz >> 7;
    const int qrow = qt * 256 + w * 32;

    // Q as B-operand, 2 fragments (q rows qrow+g*16+lr)
    bf16x8 qf[2][2];
    #pragma unroll
    for (int g = 0; g < 2; ++g) {
        const size_t qo = (size_t)(b * 2048 + qrow + g * 16 + lr) * 1024 + head * 64;
        qf[g][0] = *(const bf16x8*)&Q[qo + lg * 8];
        qf[g][1] = *(const bf16x8*)&Q[qo + 32 + lg * 8];
    }

    const bf16* Kb = K + (size_t)b * 2048 * 1024 + head * 64;
    const bf16* Vb = Vt + ((size_t)b * 1024 + head * 64) * 2048;
    const float* biasb = sbias + b * 2048;

    float m_run[2] = {-INFINITY, -INFINITY};
    f32x4 of[2][4] = {};
    f32x4 ofl[2] = {};

    bf16x8 ones8;
    #pragma unroll
    for (int j = 0; j < 8; ++j) ones8[j] = (bf16)1.0f;

    // staging: 512 K-chunks + 512 V-chunks per tile over 512 thr = 1+1 gloads.
    const int R = tid >> 3, cc = tid & 7;
    const int cs = cc ^ (R & 7);
    const int piR = ((R & 16) << 1) | ((R & 12) << 1) | ((R & 32) >> 3) | (R & 3);
    auto stage = [&](int t, int slot) {
        gload_lds16(Kb + (size_t)(t * 64 + piR) * 1024 + cs * 8,
                    &Kbuf[slot][tid * 8]);
        gload_lds16(Vb + (size_t)R * 2048 + t * 64 + cs * 8,
                    &Vbuf[slot][tid * 8]);
    };

    stage(0, 0);
    stage(1, 1);

    // bias tile 0 (pre-scaled to exp2 domain by prep)
    f32x4 b4[4];
    b4[0] = *(const f32x4*)&biasb[8 * lg];
    b4[1] = *(const f32x4*)&biasb[32 + 8 * lg];
    b4[2] = *(const f32x4*)&biasb[4 + 8 * lg];
    b4[3] = *(const f32x4*)&biasb[36 + 8 * lg];

    #pragma unroll 1
    for (int it = 0; it < 32; ++it) {
        const int slot = it & 3;
        const int tn = (it < 30) ? it + 2 : 31;
        stage(tn, (it + 2) & 3);
        asm volatile("s_waitcnt vmcnt(4)" ::: "memory");   // tile `it` + bias landed
        __builtin_amdgcn_s_barrier();
        __builtin_amdgcn_sched_barrier(0);

        // ---- prefetch bias(t+1) (consumed next iteration) ----
        const int bt = ((it < 31) ? it + 1 : 31) * 64;
        f32x4 b4n[4];
        b4n[0] = *(const f32x4*)&biasb[bt + 8 * lg];
        b4n[1] = *(const f32x4*)&biasb[bt + 32 + 8 * lg];
        b4n[2] = *(const f32x4*)&biasb[bt + 4 + 8 * lg];
        b4n[3] = *(const f32x4*)&biasb[bt + 36 + 8 * lg];

        // ---- S^T = bias + K Q^T (both frags share kf) ----
        f32x4 s[2][4];
        #pragma unroll
        for (int g = 0; g < 2; ++g)
            #pragma unroll
            for (int nt = 0; nt < 4; ++nt) s[g][nt] = b4[nt];
        #pragma unroll
        for (int ks = 0; ks < 2; ++ks) {
            const int cw = (((ks * 4 + lg) ^ (lr & 7)) << 3);
            bf16x8 kf[4];
            #pragma unroll
            for (int nt = 0; nt < 4; ++nt)
                kf[nt] = *(const bf16x8*)&Kbuf[slot][(nt * 16 + lr) * 64 + cw];
            __builtin_amdgcn_s_setprio(1);
            #pragma unroll
            for (int nt = 0; nt < 4; ++nt) {
                s[0][nt] = MFMA16(kf[nt], qf[0][ks], s[0][nt]);
                s[1][nt] = MFMA16(kf[nt], qf[1][ks], s[1][nt]);
            }
            __builtin_amdgcn_s_setprio(0);
        }

        // ---- V fragments EARLY (lgkm waits overlap softmax VALU) ----
        bf16x8 vf[2][4];
        #pragma unroll
        for (int ks = 0; ks < 2; ++ks) {
            const int cw = (((ks * 4 + lg) ^ (lr & 7)) << 3);
            #pragma unroll
            for (int dt = 0; dt < 4; ++dt)
                vf[ks][dt] = *(const bf16x8*)&Vbuf[slot][(dt * 16 + lr) * 64 + cw];
        }

        // ---- in-lane max; defer-max ----
        float rml[2];
        #pragma unroll
        for (int g = 0; g < 2; ++g) {
            float m0 = fmaxf(fmaxf(s[g][0][0], s[g][0][1]), fmaxf(s[g][0][2], s[g][0][3]));
            float m1 = fmaxf(fmaxf(s[g][1][0], s[g][1][1]), fmaxf(s[g][1][2], s[g][1][3]));
            float m2 = fmaxf(fmaxf(s[g][2][0], s[g][2][1]), fmaxf(s[g][2][2], s[g][2][3]));
            float m3 = fmaxf(fmaxf(s[g][3][0], s[g][3][1]), fmaxf(s[g][3][2], s[g][3][3]));
            rml[g] = fmaxf(fmaxf(m0, m1), fmaxf(m2, m3));
        }
        const bool need = (rml[0] > m_run[0] + 8.f) || (rml[1] > m_run[1] + 8.f);

        if (__any(need)) {            // rare: reduce + rescale both frags
            #pragma unroll
            for (int g = 0; g < 2; ++g) {
                float mx = fmaxf(rml[g], __shfl_xor(rml[g], 16, 64));
                mx = fmaxf(mx, __shfl_xor(mx, 32, 64));
                const float mnew = fmaxf(m_run[g], mx);
                const float al = exp2_hw(m_run[g] - mnew);
                m_run[g] = mnew;
                ofl[g] *= al;
                #pragma unroll
                for (int dt = 0; dt < 4; ++dt) of[g][dt] *= al;
            }
        }

        // ---- P = exp2(S - m) into lane-local B-fragments ----
        bf16x8 pb[2][2];
        #pragma unroll
        for (int g = 0; g < 2; ++g)
            #pragma unroll
            for (int i = 0; i < 4; ++i) {
                pb[g][0][i]     = (bf16)exp2_hw(s[g][0][i] - m_run[g]);
                pb[g][1][i]     = (bf16)exp2_hw(s[g][1][i] - m_run[g]);
                pb[g][0][4 + i] = (bf16)exp2_hw(s[g][2][i] - m_run[g]);
                pb[g][1][4 + i] = (bf16)exp2_hw(s[g][3][i] - m_run[g]);
            }

        // ---- O^T += V^T P^T ; l += 1·P^T ----
        __builtin_amdgcn_s_setprio(1);
        #pragma unroll
        for (int ks = 0; ks < 2; ++ks) {
            #pragma unroll
            for (int g = 0; g < 2; ++g) {
                #pragma unroll
                for (int dt = 0; dt < 4; ++dt)
                    of[g][dt] = MFMA16(vf[ks][dt], pb[g][ks], of[g][dt]);
                ofl[g] = MFMA16(ones8, pb[g][ks], ofl[g]);
            }
        }
        __builtin_amdgcn_s_setprio(0);

        #pragma unroll
        for (int nt = 0; nt < 4; ++nt) b4[nt] = b4n[nt];
    }

    // ---- finalize ----
    #pragma unroll
    for (int g = 0; g < 2; ++g) {
        const float inv = 1.0f / ofl[g][0];
        const size_t ob = (size_t)(b * 2048 + qrow + g * 16 + lr) * 1024 + head * 64;
        #pragma unroll
        for (int dt = 0; dt < 4; ++dt) {
            bf16x4 h4;
            #pragma unroll
            for (int i = 0; i < 4; ++i) h4[i] = (bf16)(of[g][dt][i] * inv);
            *(bf16x4*)&Oout[ob + dt * 16 + lg * 4] = h4;
        }
    }
}

// ---------------------------------------------------------------------------
extern "C" void kernel_launch(void* const* d_in, const int* in_sizes, int n_in,
                              void* d_out, int out_size, void* d_ws, size_t ws_size,
                              hipStream_t stream) {
    const float* query  = (const float*)d_in[0];
    const float* memory = (const float*)d_in[1];
    const float* mbias  = (const float*)d_in[2];
    const float* Wq = (const float*)d_in[3];
    const float* bq = (const float*)d_in[4];
    const float* Wk = (const float*)d_in[5];
    const float* bk = (const float*)d_in[6];
    const float* Wv = (const float*)d_in[7];
    const float* bv = (const float*)d_in[8];
    const float* Wo = (const float*)d_in[9];
    const float* bo = (const float*)d_in[10];
    float* out = (float*)d_out;

    const size_t SZ = 4096ull * 1024ull * sizeof(bf16);   // 8 MiB
    const size_t WZ = 1024ull * 1024ull * sizeof(bf16);   // 2 MiB
    char* ws = (char*)d_ws;
    bf16* Qp  = (bf16*)(ws);
    bf16* Kp  = (bf16*)(ws + SZ);       // also query_bf16 staging
    bf16* Vtp = (bf16*)(ws + 2 * SZ);
    bf16* Ap  = (bf16*)(ws + 3 * SZ);   // also memory_bf16 staging
    bf16* WTq = (bf16*)(ws + 4 * SZ);
    bf16* WTk = (bf16*)(ws + 4 * SZ + WZ);
    bf16* WTv = (bf16*)(ws + 4 * SZ + 2 * WZ);
    bf16* WTo = (bf16*)(ws + 4 * SZ + 3 * WZ);
    float* sbias = (float*)(ws + 4 * SZ + 4 * WZ);        // 16 KiB

    dim3 blk(256);
    prep_kernel<<<dim3(2048, 2, 2), blk, 0, stream>>>(
        query, memory, mbias, Wq, Wk, Wv, Wo, Kp, Ap, sbias, WTq, WTk, WTv, WTo);

    dim3 gg(16, 32);
    // Q scaled by DH^-0.5 * log2(e): softmax runs in exp2 domain.
    gemm_kernel<bf16><<<gg, blk, 0, stream>>>(Kp, WTq, bq, Qp, 0.18033688f, 0);
    gemm_kv_kernel<<<gg, blk, 0, stream>>>(Ap, WTk, WTv, bk, bv, Kp, Vtp);
    attn_kernel<<<dim3(8, 16, 2), dim3(512), 0, stream>>>(Qp, Kp, Vtp, sbias, Ap);
    gemm_kernel<float><<<gg, blk, 0, stream>>>(Ap, WTo, bo, out, 1.0f, 0);
}